// Round 7
// baseline (338.994 us; speedup 1.0000x reference)
//
#include <hip/hip_runtime.h>
#include <hip/hip_bf16.h>

#define LL 512
#define HH 128
#define NBATCH 2
#define NT 32

typedef float f32x4 __attribute__((ext_vector_type(4)));
typedef short s16x8 __attribute__((ext_vector_type(8)));
typedef unsigned int u32x4 __attribute__((ext_vector_type(4)));

__device__ __forceinline__ unsigned short f2bfu(float f){
  __hip_bfloat16 h = __float2bfloat16(f);
  return __builtin_bit_cast(unsigned short, h);
}
// max of two packed-bf16 words (both bf16-valued -> exact; max commutes with RN)
__device__ __forceinline__ unsigned int bmax2(unsigned int a, unsigned int b){
  float lo = fmaxf(__uint_as_float(a << 16), __uint_as_float(b << 16));
  float hi = fmaxf(__uint_as_float(a & 0xFFFF0000u), __uint_as_float(b & 0xFFFF0000u));
  return __float_as_uint(hi) | (__float_as_uint(lo) >> 16);
}
__device__ __forceinline__ u32x4 bmax4(u32x4 a, u32x4 b){
  u32x4 r; r[0]=bmax2(a[0],b[0]); r[1]=bmax2(a[1],b[1]);
  r[2]=bmax2(a[2],b[2]); r[3]=bmax2(a[3],b[3]); return r;
}
__device__ __forceinline__ float gelu_f(float v){
  float inner = v * fmaf(0.044715f, v*v, 1.0f);
  float e = __expf(1.5957691216f * inner);
  float s = __fdividef(1.0f, e + 1.0f);
  return fmaf(-v, s, v);
}
__device__ __forceinline__ f32x4 gelu4(f32x4 v){
  f32x4 r;
  #pragma unroll
  for (int i=0;i<4;++i) r[i] = gelu_f(v[i]);
  return r;
}

// ---- prep: t1/t2 (1024) | pfx/sfx/tilemax/ST (64) | TMR (2) | Wcb (8) ----
__global__ void prep_kernel(const float* __restrict__ x, const float* __restrict__ y,
                            const float* __restrict__ W, const float* __restrict__ bias,
                            float* __restrict__ t1, float* __restrict__ t2,
                            float* __restrict__ tilemax, short* __restrict__ pfxT,
                            short* __restrict__ sfxT, short* __restrict__ ST,
                            short* __restrict__ TMR, short* __restrict__ Wcb){
  int blk = blockIdx.x, tid = threadIdx.x;
  if (blk < NBATCH*LL){
    int b = blk >> 9, ll = blk & (LL-1);
    __shared__ float xs[HH], ys[HH];
    size_t base = ((size_t)b*LL + ll)*HH;
    if (tid < HH) xs[tid] = x[base + tid];
    else          ys[tid-HH] = y[base + tid - HH];
    __syncthreads();
    int role = tid >> 7, g = tid & (HH-1);
    const float4* wr = (const float4*)(W + (size_t)g*384 + role*HH);
    const float4* vs = (const float4*)(role ? ys : xs);
    float sA = 0.f, sB = 0.f;
    #pragma unroll
    for (int q=0;q<32;q+=2){
      float4 a = vs[q],   w1 = wr[q];
      sA = fmaf(a.x,w1.x, fmaf(a.y,w1.y, fmaf(a.z,w1.z, fmaf(a.w,w1.w, sA))));
      float4 c = vs[q+1], w2 = wr[q+1];
      sB = fmaf(c.x,w2.x, fmaf(c.y,w2.y, fmaf(c.z,w2.z, fmaf(c.w,w2.w, sB))));
    }
    float s = sA + sB;
    if (role == 0) t1[base + g] = s + bias[g];
    else           t2[base + g] = s;
  } else if (blk < NBATCH*LL + NBATCH*NT){
    int e = blk - NBATCH*LL;      // (b, tile)
    int b = e >> 5, t = e & 31;
    int role = tid >> 7, h = tid & (HH-1);
    const float* xp = x + ((size_t)b*LL + t*16)*HH + h;
    float v[16];
    #pragma unroll
    for (int r=0;r<16;++r) v[r] = xp[r*HH];
    const size_t rowb = ((size_t)(b*NT + t))*16;
    if (role == 0){
      float run = -INFINITY;
      #pragma unroll
      for (int r=0;r<16;++r){ run = fmaxf(run, v[r]);
        pfxT[(rowb + r)*HH + h] = (short)f2bfu(run); }
      tilemax[((size_t)(b*NT + t))*HH + h] = run;
    } else {
      float run = -INFINITY;
      #pragma unroll
      for (int r=15;r>=0;--r){ run = fmaxf(run, v[r]);
        sfxT[(rowb + r)*HH + h] = (short)f2bfu(run); }
      // sparse-table levels 0..3
      const size_t stb = ((size_t)(b*NT + t))*4*16;
      float cur[16];
      #pragma unroll
      for (int r=0;r<16;++r){ cur[r] = v[r];
        ST[(stb + r)*HH + h] = (short)f2bfu(v[r]); }
      #pragma unroll
      for (int k=1;k<4;++k){
        int step = 1 << (k-1);
        float nw[16];
        #pragma unroll
        for (int r=0;r<16;++r) nw[r] = fmaxf(cur[r], cur[min(r+step,15)]);
        #pragma unroll
        for (int r=0;r<16;++r){
          ST[(stb + k*16 + r)*HH + h] = (short)f2bfu(nw[r]);
          cur[r] = nw[r];
        }
      }
    }
  } else if (blk < NBATCH*LL + NBATCH*NT + NBATCH){
    int b = blk - (NBATCH*LL + NBATCH*NT);
    if (tid < HH){
      int h = tid;
      float tm[32];
      #pragma unroll
      for (int t=0;t<NT;++t){
        float m = -INFINITY;
        #pragma unroll
        for (int r=0;r<16;++r) m = fmaxf(m, x[((size_t)b*LL + t*16 + r)*HH + h]);
        tm[t] = m;
      }
      for (int t0=0;t0<NT;++t0){
        float run = -INFINITY;
        for (int t1=t0+1;t1<NT;++t1){
          unsigned short u = f2bfu(run);
          TMR[(((size_t)(b*NT)+t0)*NT + t1)*HH + h] = (short)u;
          TMR[(((size_t)(b*NT)+t1)*NT + t0)*HH + h] = (short)u;
          run = fmaxf(run, tm[t1]);
        }
      }
    }
  } else {
    int e0 = ((blk - (NBATCH*LL + NBATCH*NT + NBATCH))*256 + tid)*8;
    #pragma unroll
    for (int q=0;q<8;++q){
      int e = e0 + q; int g = e >> 7, h = e & (HH-1);
      Wcb[e] = (short)f2bfu(W[(size_t)g*384 + 256 + h]);
    }
  }
}

// ---- main: one block per output ROW (b,i); no LDS, no barriers; nt stores ----
__global__ __launch_bounds__(256, 4) void ctx_kernel(
    const float* __restrict__ t1, const float* __restrict__ t2,
    const short* __restrict__ pfxT, const short* __restrict__ sfxT,
    const short* __restrict__ ST, const short* __restrict__ TMR,
    const short* __restrict__ Wcb, float* __restrict__ out)
{
  const int tid = threadIdx.x;
  const int i = blockIdx.x, b = blockIdx.y;
  const int ti = i >> 4, ri = i & 15;
  const int w = tid >> 6, l = tid & 63, l16 = l & 15, lhi = l >> 4;
  const size_t bL = (size_t)b*LL;
  const size_t bti = (size_t)(b*NT) + ti;

  f32x4 t1v[8];
  #pragma unroll
  for (int nt=0;nt<8;++nt)
    t1v[nt] = *(const f32x4*)(t1 + (bL + i)*HH + nt*16 + lhi*4);

  u32x4 sfxo[4], pfxo[4];
  #pragma unroll
  for (int kb=0;kb<4;++kb){
    int h0 = kb*32 + lhi*8;
    sfxo[kb] = *(const u32x4*)&sfxT[(bti*16 + ri)*HH + h0];
    pfxo[kb] = *(const u32x4*)&pfxT[(bti*16 + ri)*HH + h0];
  }

  float* orow = out + ((bL + i)*LL)*HH;

  #pragma unroll
  for (int tp=0; tp<4; ++tp){
    u32x4 fr[2][4];
    #pragma unroll
    for (int s=0;s<2;++s){
      const int t = w*8 + tp*2 + s;
      if (t > ti){
        #pragma unroll
        for (int kb=0;kb<4;++kb){
          int h0 = kb*32 + lhi*8;
          u32x4 tm = *(const u32x4*)&TMR[(bti*NT + t)*HH + h0];
          u32x4 sd = *(const u32x4*)&pfxT[(((size_t)(b*NT)+t)*16 + l16)*HH + h0];
          fr[s][kb] = bmax4(sd, bmax4(sfxo[kb], tm));
        }
      } else if (t < ti){
        #pragma unroll
        for (int kb=0;kb<4;++kb){
          int h0 = kb*32 + lhi*8;
          u32x4 tm = *(const u32x4*)&TMR[(bti*NT + t)*HH + h0];
          u32x4 sd = *(const u32x4*)&sfxT[(((size_t)(b*NT)+t)*16 + l16)*HH + h0];
          fr[s][kb] = bmax4(sd, bmax4(pfxo[kb], tm));
        }
      } else {
        int a = min(ri, l16), bb = max(ri, l16);
        int len = bb - a + 1;
        int k = 31 - __clz(len); if (k > 3) k = 3;
        int r2 = bb + 1 - (1 << k);
        #pragma unroll
        for (int kb=0;kb<4;++kb){
          int h0 = kb*32 + lhi*8;
          u32x4 ua = *(const u32x4*)&ST[((bti*4 + k)*16 + a )*HH + h0];
          u32x4 ub = *(const u32x4*)&ST[((bti*4 + k)*16 + r2)*HH + h0];
          fr[s][kb] = bmax4(ua, ub);
        }
      }
    }
    #pragma unroll
    for (int nt=0; nt<8; ++nt){
      s16x8 wcf[4];
      #pragma unroll
      for (int kb=0;kb<4;++kb)
        wcf[kb] = *(const s16x8*)(Wcb + (size_t)(nt*16 + l16)*HH + kb*32 + lhi*8);
      f32x4 a0 = (f32x4){0.f,0.f,0.f,0.f}, a1 = a0;
      #pragma unroll
      for (int kb=0;kb<4;++kb){
        a0 = __builtin_amdgcn_mfma_f32_16x16x32_bf16(wcf[kb],
               __builtin_bit_cast(s16x8, fr[0][kb]), a0, 0, 0, 0);
        a1 = __builtin_amdgcn_mfma_f32_16x16x32_bf16(wcf[kb],
               __builtin_bit_cast(s16x8, fr[1][kb]), a1, 0, 0, 0);
      }
      const int g0 = nt*16 + lhi*4;
      const int j0 = (w*8 + tp*2)*16 + l16;
      f32x4 t2a = *(const f32x4*)(t2 + (bL + j0)*HH + g0);
      f32x4 t2b = *(const f32x4*)(t2 + (bL + j0 + 16)*HH + g0);
      f32x4 o0 = gelu4(a0 + t1v[nt] + t2a);
      f32x4 o1 = gelu4(a1 + t1v[nt] + t2b);
      __builtin_nontemporal_store(o0, (f32x4*)(orow + (size_t)j0*HH + g0));
      __builtin_nontemporal_store(o1, (f32x4*)(orow + (size_t)(j0+16)*HH + g0));
    }
  }
}

extern "C" void kernel_launch(void* const* d_in, const int* in_sizes, int n_in,
                              void* d_out, int out_size, void* d_ws, size_t ws_size,
                              hipStream_t stream) {
  const float* x    = (const float*)d_in[0];
  const float* y    = (const float*)d_in[1];
  const float* W    = (const float*)d_in[2];
  const float* bias = (const float*)d_in[3];
  float* out = (float*)d_out;

  float* t1      = (float*)d_ws;                      // B*L*H f32
  float* t2      = t1 + (size_t)NBATCH*LL*HH;         // B*L*H f32
  float* tilemax = t2 + (size_t)NBATCH*LL*HH;         // B*NT*H f32
  short* Wcb  = (short*)(tilemax + (size_t)NBATCH*NT*HH);  // 128*128 bf16
  short* pfxT = Wcb  + (size_t)HH*HH;                 // B*NT*16*H
  short* sfxT = pfxT + (size_t)NBATCH*NT*16*HH;       // B*NT*16*H
  short* ST   = sfxT + (size_t)NBATCH*NT*16*HH;       // B*NT*4*16*H
  short* TMR  = ST   + (size_t)NBATCH*NT*4*16*HH;     // B*NT*NT*H

  prep_kernel<<<NBATCH*LL + NBATCH*NT + NBATCH + 8, 256, 0, stream>>>(
      x, y, W, bias, t1, t2, tilemax, pfxT, sfxT, ST, TMR, Wcb);
  ctx_kernel<<<dim3(LL, NBATCH), 256, 0, stream>>>(
      t1, t2, pfxT, sfxT, ST, TMR, Wcb, out);
}